// Round 3
// baseline (265.240 us; speedup 1.0000x reference)
//
#include <hip/hip_runtime.h>

// Sorting_84894323573304: out[b,i,:] = inputs[b, argsort(sum_c inputs*w)[b,i], :]
// B=32, N=131072, C=8, fp32.
//
// Key-order hypothesis #4 (sequential FMA chain — oneDNN/BLAS gemv/gemm k-loop):
//   key = (((((((x0w0 + x1w1) + x2w2) + ... ) + x7w7, fp32, each add rounded once.
//   (w == 1.0 exactly, so FMA == mul-exact + add, matching any BLAS k-sequential kernel.)
// Stable LSD radix (4 x 8-bit) over monotone u32 key transform, payload = row idx.

#define NB   32
#define NPB  131072              // rows per batch (2^17)
#define NK   (NB * NPB)          // 4194304 keys total
#define TPB  256
#define EPT  16
#define EPB  (TPB * EPT)         // 4096 elems per block
#define BPB  (NPB / EPB)         // 32 blocks per batch
#define NBLK (NB * BPB)          // 1024
#define BINS 256

typedef unsigned long long u64;
typedef unsigned int u32;

__device__ __forceinline__ u32 fkey(float x) {
    u32 u = __float_as_uint(x);
    return u ^ ((u & 0x80000000u) ? 0xFFFFFFFFu : 0x80000000u);  // monotone fp32->u32
}

__global__ void keygen(const float* __restrict__ in, const float* __restrict__ w,
                       u64* __restrict__ out)
{
    u32 g = blockIdx.x * TPB + threadIdx.x;          // 0..NK-1
    const float4* p = (const float4*)in + (size_t)g * 2;
    float4 a = p[0], b = p[1];
    // sequential accumulation, each op rounded once (no contraction: explicit _rn)
    float k = __fmul_rn(a.x, w[0]);
    k = __fadd_rn(k, __fmul_rn(a.y, w[1]));
    k = __fadd_rn(k, __fmul_rn(a.z, w[2]));
    k = __fadd_rn(k, __fmul_rn(a.w, w[3]));
    k = __fadd_rn(k, __fmul_rn(b.x, w[4]));
    k = __fadd_rn(k, __fmul_rn(b.y, w[5]));
    k = __fadd_rn(k, __fmul_rn(b.z, w[6]));
    k = __fadd_rn(k, __fmul_rn(b.w, w[7]));
    out[g] = ((u64)fkey(k) << 32) | (u64)(g & (NPB - 1));
}

__global__ void rhist(const u64* __restrict__ src, u32* __restrict__ hist, int shift)
{
    __shared__ u32 h[BINS];
    int t = threadIdx.x;
    h[t] = 0;
    __syncthreads();
    int b = blockIdx.x / BPB, blk = blockIdx.x % BPB;
    size_t base = (size_t)b * NPB + (size_t)blk * EPB;
    int lane = t & 63;
    #pragma unroll
    for (int i = 0; i < EPT; ++i) {
        u64 v = src[base + t + i * TPB];
        u32 d = (u32)(v >> shift) & 255u;
        // wave match-any aggregation (skewed digits in high-byte passes)
        u64 m = ~0ull;
        #pragma unroll
        for (int k = 0; k < 8; ++k) {
            u64 bk = __ballot((d >> k) & 1u);
            m &= ((d >> k) & 1u) ? bk : ~bk;
        }
        if (lane == __ffsll(m) - 1) atomicAdd(&h[d], (u32)__popcll(m));
    }
    __syncthreads();
    hist[(b * BINS + t) * BPB + blk] = h[t];
}

// one block per batch: exclusive scan of 8192 entries (bin-major x block)
__global__ void rscan(u32* __restrict__ hist)
{
    int b = blockIdx.x, t = threadIdx.x;
    u32* H = hist + b * BINS * BPB;
    u32 v[32], s = 0;
    #pragma unroll
    for (int k = 0; k < 32; ++k) { v[k] = H[t * 32 + k]; s += v[k]; }
    int lane = t & 63, wid = t >> 6;
    u32 inc = s;
    #pragma unroll
    for (int off = 1; off < 64; off <<= 1) {
        u32 y = __shfl_up(inc, off, 64);
        if (lane >= off) inc += y;
    }
    __shared__ u32 wsum[4];
    if (lane == 63) wsum[wid] = inc;
    __syncthreads();
    u32 wo = 0;
    #pragma unroll
    for (int wI = 0; wI < 4; ++wI) if (wI < wid) wo += wsum[wI];
    u32 run = wo + inc - s;
    #pragma unroll
    for (int k = 0; k < 32; ++k) { u32 c = v[k]; H[t * 32 + k] = run; run += c; }
}

__launch_bounds__(TPB, 4)
__global__ void rscatter(const u64* __restrict__ src, u64* __restrict__ dst,
                         const u32* __restrict__ hist, int shift)
{
    __shared__ u32 s_key[EPB];
    __shared__ u32 s_idx[EPB];
    __shared__ u32 s_wcnt[4][BINS];
    __shared__ u32 s_dbase[BINS];
    __shared__ u32 s_gbase[BINS];
    __shared__ u32 s_wsum[4];
    int t = threadIdx.x, lane = t & 63, wid = t >> 6;
    int b = blockIdx.x / BPB, blk = blockIdx.x % BPB;
    size_t base = (size_t)b * NPB + (size_t)blk * EPB + (size_t)wid * 1024;

    #pragma unroll
    for (int k = 0; k < 4; ++k) ((u32*)s_wcnt)[t + k * TPB] = 0;
    __syncthreads();

    // wave w owns elements [w*1024, w*1024+1024); element order = (step, lane)
    u64 v[EPT];
    u32 rnk[EPT];
    #pragma unroll
    for (int i = 0; i < EPT; ++i) v[i] = src[base + i * 64 + lane];

    #pragma unroll
    for (int i = 0; i < EPT; ++i) {
        u32 d = (u32)(v[i] >> shift) & 255u;
        u64 m = ~0ull;
        #pragma unroll
        for (int k = 0; k < 8; ++k) {
            u64 bk = __ballot((d >> k) & 1u);
            m &= ((d >> k) & 1u) ? bk : ~bk;
        }
        int leader = __ffsll(m) - 1;
        u32 baseCnt = 0;
        if (lane == leader) {
            baseCnt = s_wcnt[wid][d];
            s_wcnt[wid][d] = baseCnt + (u32)__popcll(m);
        }
        baseCnt = __shfl(baseCnt, leader, 64);
        rnk[i] = baseCnt + (u32)__popcll(m & ((1ull << lane) - 1ull));
        __builtin_amdgcn_wave_barrier();   // keep per-step LDS counter order
    }
    __syncthreads();

    // t == digit: wave prefixes + block digit scan + global bases
    u32 c0 = s_wcnt[0][t], c1 = s_wcnt[1][t], c2 = s_wcnt[2][t], c3 = s_wcnt[3][t];
    u32 tot = c0 + c1 + c2 + c3;
    s_wcnt[0][t] = 0; s_wcnt[1][t] = c0; s_wcnt[2][t] = c0 + c1; s_wcnt[3][t] = c0 + c1 + c2;
    u32 inc = tot;
    #pragma unroll
    for (int off = 1; off < 64; off <<= 1) {
        u32 y = __shfl_up(inc, off, 64);
        if (lane >= off) inc += y;
    }
    if (lane == 63) s_wsum[wid] = inc;
    __syncthreads();
    u32 wo = 0;
    #pragma unroll
    for (int wI = 0; wI < 4; ++wI) if (wI < wid) wo += s_wsum[wI];
    s_dbase[t] = wo + inc - tot;
    s_gbase[t] = hist[(b * BINS + t) * BPB + blk];
    __syncthreads();

    // stable local permute through LDS
    #pragma unroll
    for (int i = 0; i < EPT; ++i) {
        u32 d = (u32)(v[i] >> shift) & 255u;
        u32 pos = s_dbase[d] + s_wcnt[wid][d] + rnk[i];
        s_key[pos] = (u32)(v[i] >> 32);
        s_idx[pos] = (u32)v[i];
    }
    __syncthreads();

    // coalesced striped global store (digit runs are contiguous)
    int kshift = shift - 32;
    #pragma unroll
    for (int i = 0; i < EPT; ++i) {
        int j = i * TPB + t;
        u32 key = s_key[j], idx = s_idx[j];
        u32 d = (key >> kshift) & 255u;
        u32 gpos = s_gbase[d] + (u32)j - s_dbase[d];
        dst[(size_t)b * NPB + gpos] = ((u64)key << 32) | (u64)idx;
    }
}

__global__ void gatherk(const u64* __restrict__ sorted, const float* __restrict__ in,
                        float* __restrict__ out)
{
    u32 g = blockIdx.x * TPB + threadIdx.x;
    u64 v = sorted[g];
    u32 n = (u32)v;                       // row index within batch
    u32 b = g >> 17;                      // NPB = 2^17
    const float4* s = (const float4*)in + (((size_t)b << 17) + n) * 2;
    float4 x = s[0], y = s[1];
    float4* d4 = (float4*)out + (size_t)g * 2;
    d4[0] = x; d4[1] = y;
}

extern "C" void kernel_launch(void* const* d_in, const int* in_sizes, int n_in,
                              void* d_out, int out_size, void* d_ws, size_t ws_size,
                              hipStream_t stream)
{
    const float* in = (const float*)d_in[0];
    const float* w  = (const float*)d_in[1];
    float* out = (float*)d_out;

    // ws: bufA (NK u64 = 33.5MB) + hist (32*256*32 u32 = 1MB). bufB aliases d_out
    // (134MB fp32), fully rewritten by gatherk every call -> deterministic.
    u64* bufA = (u64*)d_ws;
    u64* bufB = (u64*)d_out;
    u32* hist = (u32*)((char*)d_ws + (size_t)NK * 8);

    keygen<<<NK / TPB, TPB, 0, stream>>>(in, w, bufA);

    u64 *cur = bufA, *alt = bufB;
    for (int p = 0; p < 4; ++p) {
        int shift = 32 + 8 * p;
        rhist<<<NBLK, TPB, 0, stream>>>(cur, hist, shift);
        rscan<<<NB, TPB, 0, stream>>>(hist);
        rscatter<<<NBLK, TPB, 0, stream>>>(cur, alt, hist, shift);
        u64* tmp = cur; cur = alt; alt = tmp;
    }
    // after an even number of passes, sorted pairs are back in bufA
    gatherk<<<NK / TPB, TPB, 0, stream>>>(cur, in, out);
}

// Round 4
// 222.791 us; speedup vs baseline: 1.1905x; 1.1905x over previous
//
#include <hip/hip_runtime.h>

// Sorting_84894323573304: out[b,i,:] = inputs[b, argsort(sum_c inputs*w)[b,i], :]
// B=32, N=131072, C=8, fp32.
//
// Key order (verified R3, absmax=0): sequential FMA chain (BLAS k-loop):
//   key = (((x0w0 + x1w1) + x2w2) + ... + x7w7), fp32, each add rounded once.
// Stable LSD radix (4 x 8-bit), payload = row idx. This round: fused
// keygen+hist0, fused final-pass scatter+row-gather, XCD batch-affinity swizzle.

#define NB   32
#define NPB  131072              // rows per batch (2^17)
#define NK   (NB * NPB)          // 4194304 keys total
#define TPB  256
#define EPT  16
#define EPB  (TPB * EPT)         // 4096 elems per block
#define BPB  (NPB / EPB)         // 32 blocks per batch
#define NBLK (NB * BPB)          // 1024
#define BINS 256

typedef unsigned long long u64;
typedef unsigned int u32;

__device__ __forceinline__ u32 fkey(float x) {
    u32 u = __float_as_uint(x);
    return u ^ ((u & 0x80000000u) ? 0xFFFFFFFFu : 0x80000000u);  // monotone fp32->u32
}

__device__ __forceinline__ u64 matchany(u32 d) {
    u64 m = ~0ull;
    #pragma unroll
    for (int k = 0; k < 8; ++k) {
        u64 bk = __ballot((d >> k) & 1u);
        m &= ((d >> k) & 1u) ? bk : ~bk;
    }
    return m;
}

// fused keygen + pass-0 (shift=32) histogram
__global__ void khist0(const float* __restrict__ in, const float* __restrict__ w,
                       u64* __restrict__ outp, u32* __restrict__ hist)
{
    __shared__ u32 h[BINS];
    int t = threadIdx.x;
    h[t] = 0;
    __syncthreads();
    int b = blockIdx.x / BPB, blk = blockIdx.x % BPB;
    size_t base = (size_t)b * NPB + (size_t)blk * EPB;
    int lane = t & 63;
    float w0 = w[0], w1 = w[1], w2 = w[2], w3 = w[3];
    float w4 = w[4], w5 = w[5], w6 = w[6], w7 = w[7];
    #pragma unroll
    for (int i = 0; i < EPT; ++i) {
        size_t row = base + t + i * TPB;
        const float4* p = (const float4*)in + row * 2;
        float4 a = p[0], c = p[1];
        // sequential accumulation, each op rounded once (matches np/BLAS k-loop)
        float k = __fmul_rn(a.x, w0);
        k = __fadd_rn(k, __fmul_rn(a.y, w1));
        k = __fadd_rn(k, __fmul_rn(a.z, w2));
        k = __fadd_rn(k, __fmul_rn(a.w, w3));
        k = __fadd_rn(k, __fmul_rn(c.x, w4));
        k = __fadd_rn(k, __fmul_rn(c.y, w5));
        k = __fadd_rn(k, __fmul_rn(c.z, w6));
        k = __fadd_rn(k, __fmul_rn(c.w, w7));
        u32 fk = fkey(k);
        outp[row] = ((u64)fk << 32) | (u64)((u32)row & (NPB - 1));
        u32 d = fk & 255u;
        u64 m = matchany(d);
        if (lane == __ffsll(m) - 1) atomicAdd(&h[d], (u32)__popcll(m));
    }
    __syncthreads();
    hist[(b * BINS + t) * BPB + blk] = h[t];
}

__global__ void rhist(const u64* __restrict__ src, u32* __restrict__ hist, int shift)
{
    __shared__ u32 h[BINS];
    int t = threadIdx.x;
    h[t] = 0;
    __syncthreads();
    int b = blockIdx.x / BPB, blk = blockIdx.x % BPB;
    size_t base = (size_t)b * NPB + (size_t)blk * EPB;
    int lane = t & 63;
    #pragma unroll
    for (int i = 0; i < EPT; ++i) {
        u64 v = src[base + t + i * TPB];
        u32 d = (u32)(v >> shift) & 255u;
        u64 m = matchany(d);
        if (lane == __ffsll(m) - 1) atomicAdd(&h[d], (u32)__popcll(m));
    }
    __syncthreads();
    hist[(b * BINS + t) * BPB + blk] = h[t];
}

// one block per batch: exclusive scan of 8192 entries (bin-major x block)
__global__ void rscan(u32* __restrict__ hist)
{
    int b = blockIdx.x, t = threadIdx.x;
    u32* H = hist + b * BINS * BPB;
    u32 v[32], s = 0;
    #pragma unroll
    for (int k = 0; k < 32; ++k) { v[k] = H[t * 32 + k]; s += v[k]; }
    int lane = t & 63, wid = t >> 6;
    u32 inc = s;
    #pragma unroll
    for (int off = 1; off < 64; off <<= 1) {
        u32 y = __shfl_up(inc, off, 64);
        if (lane >= off) inc += y;
    }
    __shared__ u32 wsum[4];
    if (lane == 63) wsum[wid] = inc;
    __syncthreads();
    u32 wo = 0;
    #pragma unroll
    for (int wI = 0; wI < 4; ++wI) if (wI < wid) wo += wsum[wI];
    u32 run = wo + inc - s;
    #pragma unroll
    for (int k = 0; k < 32; ++k) { u32 c = v[k]; H[t * 32 + k] = run; run += c; }
}

// shared ranking/permute body for scatter passes.
// After this, s_key/s_idx hold the block's elements in locally-sorted order,
// s_dbase[d] = local base of digit run d, s_gbase[d] = global base for this block.
#define RANK_PERMUTE_BODY(SRC_EXPR)                                             \
    int t = threadIdx.x, lane = t & 63, wid = t >> 6;                           \
    size_t base = (size_t)b * NPB + (size_t)blk * EPB + (size_t)wid * 1024;     \
    _Pragma("unroll")                                                           \
    for (int k = 0; k < 4; ++k) ((u32*)s_wcnt)[t + k * TPB] = 0;                \
    __syncthreads();                                                            \
    u64 v[EPT];                                                                 \
    u32 rnk[EPT];                                                               \
    _Pragma("unroll")                                                           \
    for (int i = 0; i < EPT; ++i) v[i] = (SRC_EXPR);                            \
    _Pragma("unroll")                                                           \
    for (int i = 0; i < EPT; ++i) {                                             \
        u32 d = (u32)(v[i] >> shift) & 255u;                                    \
        u64 m = matchany(d);                                                    \
        int leader = __ffsll(m) - 1;                                            \
        u32 baseCnt = 0;                                                        \
        if (lane == leader) {                                                   \
            baseCnt = s_wcnt[wid][d];                                           \
            s_wcnt[wid][d] = baseCnt + (u32)__popcll(m);                        \
        }                                                                       \
        baseCnt = __shfl(baseCnt, leader, 64);                                  \
        rnk[i] = baseCnt + (u32)__popcll(m & ((1ull << lane) - 1ull));          \
        __builtin_amdgcn_wave_barrier();                                        \
    }                                                                           \
    __syncthreads();                                                            \
    u32 c0 = s_wcnt[0][t], c1 = s_wcnt[1][t], c2 = s_wcnt[2][t], c3 = s_wcnt[3][t]; \
    u32 tot = c0 + c1 + c2 + c3;                                                \
    s_wcnt[0][t] = 0; s_wcnt[1][t] = c0; s_wcnt[2][t] = c0 + c1;                \
    s_wcnt[3][t] = c0 + c1 + c2;                                                \
    u32 inc = tot;                                                              \
    _Pragma("unroll")                                                           \
    for (int off = 1; off < 64; off <<= 1) {                                    \
        u32 y = __shfl_up(inc, off, 64);                                        \
        if (lane >= off) inc += y;                                              \
    }                                                                           \
    if (lane == 63) s_wsum[wid] = inc;                                          \
    __syncthreads();                                                            \
    u32 wo = 0;                                                                 \
    _Pragma("unroll")                                                           \
    for (int wI = 0; wI < 4; ++wI) if (wI < wid) wo += s_wsum[wI];              \
    s_dbase[t] = wo + inc - tot;                                                \
    s_gbase[t] = hist[(b * BINS + t) * BPB + blk];                              \
    __syncthreads();                                                            \
    _Pragma("unroll")                                                           \
    for (int i = 0; i < EPT; ++i) {                                             \
        u32 d = (u32)(v[i] >> shift) & 255u;                                    \
        u32 pos = s_dbase[d] + s_wcnt[wid][d] + rnk[i];                         \
        s_key[pos] = (u32)(v[i] >> 32);                                         \
        s_idx[pos] = (u32)v[i];                                                 \
    }                                                                           \
    __syncthreads();

__launch_bounds__(TPB, 4)
__global__ void rscatter(const u64* __restrict__ src, u64* __restrict__ dst,
                         const u32* __restrict__ hist, int shift)
{
    __shared__ u32 s_key[EPB];
    __shared__ u32 s_idx[EPB];
    __shared__ u32 s_wcnt[4][BINS];
    __shared__ u32 s_dbase[BINS];
    __shared__ u32 s_gbase[BINS];
    __shared__ u32 s_wsum[4];
    int b = blockIdx.x / BPB, blk = blockIdx.x % BPB;
    RANK_PERMUTE_BODY(src[base + i * 64 + lane])

    // coalesced striped global store (digit runs are contiguous)
    int kshift = shift - 32;
    #pragma unroll
    for (int i = 0; i < EPT; ++i) {
        int j = i * TPB + t;
        u32 key = s_key[j], idx = s_idx[j];
        u32 d = (key >> kshift) & 255u;
        u32 gpos = s_gbase[d] + (u32)j - s_dbase[d];
        dst[(size_t)b * NPB + gpos] = ((u64)key << 32) | (u64)idx;
    }
}

// final MSB pass fused with the row gather: writes output rows directly.
__launch_bounds__(TPB, 4)
__global__ void rscatgat(const u64* __restrict__ src, const float* __restrict__ in,
                         float* __restrict__ out, const u32* __restrict__ hist)
{
    __shared__ u32 s_key[EPB];
    __shared__ u32 s_idx[EPB];
    __shared__ u32 s_wcnt[4][BINS];
    __shared__ u32 s_dbase[BINS];
    __shared__ u32 s_gbase[BINS];
    __shared__ u32 s_wsum[4];
    const int shift = 56;
    // XCD batch-affinity swizzle: all 32 blocks of batch b land on XCD b&7,
    // so in-flight random row reads stay within ~1-2 batches (4-8MB) per XCD L2.
    int i0 = blockIdx.x;
    int xcd = i0 & 7, j0 = i0 >> 3;
    int b = xcd + 8 * (j0 >> 5), blk = j0 & 31;
    RANK_PERMUTE_BODY(src[base + i * 64 + lane])

    const float4* inb = (const float4*)in + ((size_t)b << 18); // b*NPB*2 float4s
    float4* outb = (float4*)out + ((size_t)b << 18);
    #pragma unroll
    for (int i = 0; i < EPT; ++i) {
        int j = i * TPB + t;
        u32 key = s_key[j], idx = s_idx[j];
        u32 d = (key >> 24);
        u32 gpos = s_gbase[d] + (u32)j - s_dbase[d];
        const float4* s = inb + (size_t)idx * 2;
        float4 x = s[0], y = s[1];
        float4* drow = outb + (size_t)gpos * 2;
        drow[0] = x; drow[1] = y;
    }
}

extern "C" void kernel_launch(void* const* d_in, const int* in_sizes, int n_in,
                              void* d_out, int out_size, void* d_ws, size_t ws_size,
                              hipStream_t stream)
{
    const float* in = (const float*)d_in[0];
    const float* w  = (const float*)d_in[1];
    float* out = (float*)d_out;

    // ws: bufA (NK u64 = 33.5MB) + hist (32*256*32 u32 = 1MB).
    // bufB aliases d_out (134MB, fully rewritten by rscatgat -> deterministic).
    // Ping-pong: keygen->B, p0 B->A, p1 A->B, p2 B->A, p3 reads A -> rows to out.
    u64* A = (u64*)d_ws;
    u64* B = (u64*)d_out;
    u32* hist = (u32*)((char*)d_ws + (size_t)NK * 8);

    khist0<<<NBLK, TPB, 0, stream>>>(in, w, B, hist);
    rscan<<<NB, TPB, 0, stream>>>(hist);
    rscatter<<<NBLK, TPB, 0, stream>>>(B, A, hist, 32);

    rhist<<<NBLK, TPB, 0, stream>>>(A, hist, 40);
    rscan<<<NB, TPB, 0, stream>>>(hist);
    rscatter<<<NBLK, TPB, 0, stream>>>(A, B, hist, 40);

    rhist<<<NBLK, TPB, 0, stream>>>(B, hist, 48);
    rscan<<<NB, TPB, 0, stream>>>(hist);
    rscatter<<<NBLK, TPB, 0, stream>>>(B, A, hist, 48);

    rhist<<<NBLK, TPB, 0, stream>>>(A, hist, 56);
    rscan<<<NB, TPB, 0, stream>>>(hist);
    rscatgat<<<NBLK, TPB, 0, stream>>>(A, in, out, hist);
}